// Round 1
// baseline (16669.917 us; speedup 1.0000x reference)
//
#include <hip/hip_runtime.h>

typedef unsigned short ushort_t;
typedef unsigned int uint_t;
typedef __attribute__((ext_vector_type(8))) short short8;
typedef __attribute__((ext_vector_type(4))) float f32x4;

#define MFMA16(a, b, c) __builtin_amdgcn_mfma_f32_16x16x32_bf16((a), (b), (c), 0, 0, 0)

__device__ __forceinline__ ushort_t f2bf(float f) {
  union { float f; uint_t u; } v; v.f = f;
  uint_t r = v.u + 0x7fffu + ((v.u >> 16) & 1u);
  return (ushort_t)(r >> 16);
}
__device__ __forceinline__ float sigm(float x) { return 1.f / (1.f + __expf(-x)); }

// ---------------- workspace layout (bytes) ----------------
#define OFF_XBF  0UL            // bf16 x       [256][256][128]  16777216
#define OFF_W1T  16777216UL     // bf16 W1^T    [1536][128]      393216
#define OFF_R1T  17170432UL     // bf16 R1^T    [1536][512]      1572864
#define OFF_W2T  18743296UL     // bf16 W2^T    [1536][512]      1572864
#define OFF_R2T  20316160UL     // bf16 R2^T    [1536][512]      1572864
#define OFF_W3T  21889024UL     // bf16 W3^T    [192][512]       196608
#define OFF_R3T  22085632UL     // bf16 R3^T    [192][64]        24576
#define OFF_H1R  22110208UL     // bf16 ring    [4][256][512]    1048576
#define OFF_H2R  23158784UL     // bf16 ring    [4][256][512]    1048576
#define OFF_H3R  24207360UL     // bf16 ring    [4][256][64]     131072
#define OFF_CNT  24338432UL     // uint cnt[64] (chain*16)       256

// ---------------- init kernels ----------------
__global__ void k_cvtx(const float* __restrict__ x, ushort_t* __restrict__ xb) {
  const int i = blockIdx.x * 256 + threadIdx.x;   // 2097152 threads, 4 elems each
  const float4 v = ((const float4*)x)[i];
  ushort4 o;
  o.x = f2bf(v.x); o.y = f2bf(v.y); o.z = f2bf(v.z); o.w = f2bf(v.w);
  ((ushort4*)xb)[i] = o;
}

// src [K][G] fp32 -> dst [G][K] bf16
__global__ void k_tr(const float* __restrict__ src, ushort_t* __restrict__ dst,
                     int K, int G, int n) {
  const int i = blockIdx.x * 256 + threadIdx.x;
  if (i >= n) return;
  const int g = i / K, k = i - g * K;
  dst[i] = f2bf(src[(size_t)k * G + g]);
}

__global__ void k_zero(uint_t* h1, uint_t* h2, uint_t* h3, uint_t* cnt) {
  const int i = blockIdx.x * 256 + threadIdx.x;
  if (i < 65536) h1[196608 + i] = 0;                    // h1 ring slot 3
  else if (i < 131072) h2[196608 + (i - 65536)] = 0;    // h2 ring slot 3
  else if (i < 139264) h3[24576 + (i - 131072)] = 0;    // h3 ring slot 3
  else if (i < 139328) cnt[i - 139264] = 0;             // chain counters
}

// ---------------- persistent pipelined GRU ----------------
// grid = 256 blocks x 256 threads. blockIdx = xcd + 8*slot (XCD round-robin heuristic).
// chain = xcd>>1 (64 WGs/chain on one XCD pair). member<32 -> layer1 colgroup,
// else layer2 colgroup. layer1 colgroups 28..31 also run layer3 (dual role).
// Superstep s: layer1 computes t=s, layer2 t=s-1, layer3 t=s-2. One chain barrier/step.
__global__ __launch_bounds__(256, 1)
void gru_main(const ushort_t* __restrict__ xbf,
              const ushort_t* __restrict__ W1t, const ushort_t* __restrict__ R1t,
              const ushort_t* __restrict__ W2t, const ushort_t* __restrict__ R2t,
              const ushort_t* __restrict__ W3t, const ushort_t* __restrict__ R3t,
              const float* __restrict__ b1, const float* __restrict__ b2,
              const float* __restrict__ b3,
              ushort_t* __restrict__ h1r, ushort_t* __restrict__ h2r,
              ushort_t* __restrict__ h3r,
              uint_t* __restrict__ cnt, float* __restrict__ out) {
  // LDS: layer1: R-slice 48 rows x stride 520 (pad -> 2-way banks) = [0,24960) ushorts,
  //              W1-slice 48 x 136 = [24960,31488).
  //      layer2: R2-slice [0,24960); reduce scratch floats at ushort 24960 (12 KB).
  __shared__ ushort_t smem[31488];
  const int tid = threadIdx.x;
  const int bid = blockIdx.x;
  const int xcd = bid & 7;
  const int slot = bid >> 3;
  const int chain = xcd >> 1;
  const int member = ((xcd & 1) << 5) | slot;   // 0..63
  const bool isL1 = (member < 32);
  const int cg = isL1 ? member : (member - 32); // colgroup: 16 u-cols
  const bool isL3 = isL1 && (cg >= 28);
  const int cg3 = cg - 28;
  const int b0 = chain << 6;                    // 64 batch rows per chain
  const int lane = tid & 63;
  const int wid = tid >> 6;
  const int l15 = lane & 15;
  const int quad = lane >> 4;
  const int m0 = wid << 4;                      // layer1/3: wave = one 16-row M tile
  const int ucol = (cg << 4) + l15;
  const int u3col = (cg3 << 4) + l15;

  // ---- stage weight slices to LDS ----
  if (isL1) {
    for (int i = tid; i < 3072; i += 256) {     // R1 slice: 48 rows x 512
      const int dr = i >> 6, dc = (i & 63) << 3;
      const int g = ((dr >> 4) << 9) + (cg << 4) + (dr & 15);
      *(short8*)&smem[dr * 520 + dc] = *(const short8*)&R1t[(size_t)g * 512 + dc];
    }
    for (int i = tid; i < 768; i += 256) {      // W1 slice: 48 rows x 128
      const int dr = i >> 4, dc = (i & 15) << 3;
      const int g = ((dr >> 4) << 9) + (cg << 4) + (dr & 15);
      *(short8*)&smem[24960 + dr * 136 + dc] = *(const short8*)&W1t[(size_t)g * 128 + dc];
    }
  } else {
    for (int i = tid; i < 3072; i += 256) {     // R2 slice
      const int dr = i >> 6, dc = (i & 63) << 3;
      const int g = ((dr >> 4) << 9) + (cg << 4) + (dr & 15);
      *(short8*)&smem[dr * 520 + dc] = *(const short8*)&R2t[(size_t)g * 512 + dc];
    }
  }

  // ---- per-lane biases (constant over time) ----
  float bz0, brr0, bh0, bz1, brr1, bh1;
  {
    const float* bb = isL1 ? b1 : b2;
    bz0 = bb[ucol];        brr0 = bb[512 + ucol];  bh0 = bb[1024 + ucol];
    bz1 = bb[1536 + ucol]; brr1 = bb[2048 + ucol]; bh1 = bb[2560 + ucol];
  }
  float cz0 = 0, cr0 = 0, ch0 = 0, cz1 = 0, cr1 = 0, ch1 = 0;
  if (isL3) {
    cz0 = b3[u3col];       cr0 = b3[64 + u3col];   ch0 = b3[128 + u3col];
    cz1 = b3[192 + u3col]; cr1 = b3[256 + u3col];  ch1 = b3[320 + u3col];
  }

  // ---- layer2: W2 slice register-resident; wave = (mh,kh) 2x2 M/K split ----
  const int kh = wid & 1, mh = wid >> 1;
  short8 w2f[3][8];
  if (!isL1) {
#pragma unroll
    for (int nt = 0; nt < 3; ++nt)
#pragma unroll
      for (int k = 0; k < 8; ++k)
        w2f[nt][k] = *(const short8*)&W2t[(size_t)((nt << 9) + ucol) * 512 +
                                          (((kh << 3) + k) << 5) + (quad << 3)];
  }
  __syncthreads();

  float hOwn1[4] = {0, 0, 0, 0};
  float hOwn2[8] = {0, 0, 0, 0, 0, 0, 0, 0};
  float hOwn3[4] = {0, 0, 0, 0};
  float* scr = (float*)&smem[24960];
  const f32x4 zero4 = {0.f, 0.f, 0.f, 0.f};

  for (int s = 0; s < 258; ++s) {
    if (isL1) {
      if (s < 256) {
        f32x4 ax[3] = {zero4, zero4, zero4};
        f32x4 ar[3] = {zero4, zero4, zero4};
        // xp1 = x[:,t,:] @ W1slice  (K=128)
        const ushort_t* xr = xbf + (((size_t)(b0 + m0 + l15)) * 256 + s) * 128;
#pragma unroll
        for (int kk = 0; kk < 4; ++kk) {
          const short8 a = *(const short8*)&xr[(kk << 5) + (quad << 3)];
#pragma unroll
          for (int nt = 0; nt < 3; ++nt) {
            const short8 b = *(const short8*)&smem[24960 + ((nt << 4) + l15) * 136 +
                                                   (kk << 5) + (quad << 3)];
            ax[nt] = MFMA16(a, b, ax[nt]);
          }
        }
        // rec = h1_t @ R1slice  (K=512), h1_t from ring slot (s-1)&3
        const ushort_t* hr =
            h1r + (((size_t)((s - 1) & 3)) * 256 + (b0 + m0 + l15)) * 512;
#pragma unroll
        for (int kk = 0; kk < 16; ++kk) {
          const short8 a = *(const short8*)&hr[(kk << 5) + (quad << 3)];
#pragma unroll
          for (int nt = 0; nt < 3; ++nt) {
            const short8 b =
                *(const short8*)&smem[((nt << 4) + l15) * 520 + (kk << 5) + (quad << 3)];
            ar[nt] = MFMA16(a, b, ar[nt]);
          }
        }
        const int wslot = s & 3;
#pragma unroll
        for (int r = 0; r < 4; ++r) {
          const float z = sigm(ax[0][r] + bz0 + ar[0][r] + bz1);
          const float rg = sigm(ax[1][r] + brr0 + ar[1][r] + brr1);
          const float hh = fmaxf(ax[2][r] + bh0 + rg * (ar[2][r] + bh1), 0.f);
          const float hn = z * hOwn1[r] + (1.f - z) * hh;
          hOwn1[r] = hn;
          const int row = b0 + m0 + (quad << 2) + r;
          h1r[((size_t)wslot * 256 + row) * 512 + ucol] = f2bf(hn);
        }
      }
      if (isL3 && s >= 2) {
        const int t3 = s - 2;
        f32x4 qx[3] = {zero4, zero4, zero4};
        f32x4 qr[3] = {zero4, zero4, zero4};
        // xp3 = h2seq[t3] @ W3slice (K=512), streamed B from L2
        const ushort_t* h2row =
            h2r + (((size_t)((s - 2) & 3)) * 256 + (b0 + m0 + l15)) * 512;
#pragma unroll
        for (int kk = 0; kk < 16; ++kk) {
          const short8 a = *(const short8*)&h2row[(kk << 5) + (quad << 3)];
#pragma unroll
          for (int nt = 0; nt < 3; ++nt) {
            const short8 b = *(const short8*)&W3t[(size_t)((nt << 6) + u3col) * 512 +
                                                  (kk << 5) + (quad << 3)];
            qx[nt] = MFMA16(a, b, qx[nt]);
          }
        }
        // rec3 = h3_{t3} @ R3slice (K=64)
        const ushort_t* h3row =
            h3r + (((size_t)((s - 3) & 3)) * 256 + (b0 + m0 + l15)) * 64;
#pragma unroll
        for (int kk = 0; kk < 2; ++kk) {
          const short8 a = *(const short8*)&h3row[(kk << 5) + (quad << 3)];
#pragma unroll
          for (int nt = 0; nt < 3; ++nt) {
            const short8 b = *(const short8*)&R3t[(size_t)((nt << 6) + u3col) * 64 +
                                                  (kk << 5) + (quad << 3)];
            qr[nt] = MFMA16(a, b, qr[nt]);
          }
        }
        const int w3 = (s - 2) & 3;
#pragma unroll
        for (int r = 0; r < 4; ++r) {
          const float z = sigm(qx[0][r] + cz0 + qr[0][r] + cz1);
          const float rg = sigm(qx[1][r] + cr0 + qr[1][r] + cr1);
          const float hh = sigm(qx[2][r] + ch0 + rg * (qr[2][r] + ch1));
          const float hn = z * hOwn3[r] + (1.f - z) * hh;
          hOwn3[r] = hn;
          const int row = b0 + m0 + (quad << 2) + r;
          h3r[((size_t)w3 * 256 + row) * 64 + u3col] = f2bf(hn);
          out[((size_t)row * 256 + t3) * 64 + u3col] = hn;
        }
      }
    } else {
      if (s >= 1 && s < 257) {
        f32x4 px[6] = {zero4, zero4, zero4, zero4, zero4, zero4};
        f32x4 pr[6] = {zero4, zero4, zero4, zero4, zero4, zero4};
        const size_t hxb = ((size_t)((s - 1) & 3)) * 256;  // h1seq[t2]
        const size_t hrb = ((size_t)((s - 2) & 3)) * 256;  // h2_{t2}
        const ushort_t* h1p[2];
        const ushort_t* h2p[2];
#pragma unroll
        for (int mt2 = 0; mt2 < 2; ++mt2) {
          const int mrow = b0 + (((mh << 1) + mt2) << 4) + l15;
          h1p[mt2] = h1r + (hxb + mrow) * 512;
          h2p[mt2] = h2r + (hrb + mrow) * 512;
        }
#pragma unroll
        for (int k = 0; k < 8; ++k) {
          const int koff = (((kh << 3) + k) << 5) + (quad << 3);
          short8 brg[3];
#pragma unroll
          for (int nt = 0; nt < 3; ++nt)
            brg[nt] = *(const short8*)&smem[((nt << 4) + l15) * 520 + koff];
#pragma unroll
          for (int mt2 = 0; mt2 < 2; ++mt2) {
            const short8 a1 = *(const short8*)&h1p[mt2][koff];
            const short8 a2 = *(const short8*)&h2p[mt2][koff];
#pragma unroll
            for (int nt = 0; nt < 3; ++nt) {
              px[mt2 * 3 + nt] = MFMA16(a1, w2f[nt][k], px[mt2 * 3 + nt]);
              pr[mt2 * 3 + nt] = MFMA16(a2, brg[nt], pr[mt2 * 3 + nt]);
            }
          }
        }
        // cross-wave K reduction (kh=1 -> kh=0) via LDS scratch, 2 phases
        __syncthreads();
        if (kh == 1) {
#pragma unroll
          for (int t = 0; t < 6; ++t)
            *(f32x4*)&scr[(((mh * 6 + t) << 6) + lane) << 2] = pr[t];
        }
        __syncthreads();
        if (kh == 0) {
#pragma unroll
          for (int t = 0; t < 6; ++t)
            pr[t] += *(const f32x4*)&scr[(((mh * 6 + t) << 6) + lane) << 2];
        }
        __syncthreads();
        if (kh == 1) {
#pragma unroll
          for (int t = 0; t < 6; ++t)
            *(f32x4*)&scr[(((mh * 6 + t) << 6) + lane) << 2] = px[t];
        }
        __syncthreads();
        if (kh == 0) {
          const int wslot = (s - 1) & 3;
#pragma unroll
          for (int t = 0; t < 6; ++t)
            px[t] += *(const f32x4*)&scr[(((mh * 6 + t) << 6) + lane) << 2];
#pragma unroll
          for (int mt2 = 0; mt2 < 2; ++mt2) {
#pragma unroll
            for (int r = 0; r < 4; ++r) {
              const int t0 = mt2 * 3;
              const float z = sigm(px[t0][r] + bz0 + pr[t0][r] + bz1);
              const float rg = sigm(px[t0 + 1][r] + brr0 + pr[t0 + 1][r] + brr1);
              const float hh =
                  fmaxf(px[t0 + 2][r] + bh0 + rg * (pr[t0 + 2][r] + bh1), 0.f);
              const float hn = z * hOwn2[mt2 * 4 + r] + (1.f - z) * hh;
              hOwn2[mt2 * 4 + r] = hn;
              const int row = b0 + (((mh << 1) + mt2) << 4) + (quad << 2) + r;
              h2r[((size_t)wslot * 256 + row) * 512 + ucol] = f2bf(hn);
            }
          }
        }
      }
    }
    // ---- chain barrier (64 WGs, monotonic counter) ----
    __threadfence();
    __syncthreads();
    if (tid == 0) {
      __hip_atomic_fetch_add(&cnt[chain << 4], 1u, __ATOMIC_RELEASE,
                             __HIP_MEMORY_SCOPE_AGENT);
      const uint_t tgt = (uint_t)(s + 1) * 64u;
      while (__hip_atomic_load(&cnt[chain << 4], __ATOMIC_ACQUIRE,
                               __HIP_MEMORY_SCOPE_AGENT) < tgt) {
        __builtin_amdgcn_s_sleep(8);
      }
    }
    __syncthreads();
    __threadfence();
  }
}

extern "C" void kernel_launch(void* const* d_in, const int* in_sizes, int n_in,
                              void* d_out, int out_size, void* d_ws, size_t ws_size,
                              hipStream_t stream) {
  const float* x  = (const float*)d_in[0];
  const float* W1 = (const float*)d_in[1];
  const float* R1 = (const float*)d_in[2];
  const float* b1 = (const float*)d_in[3];
  const float* W2 = (const float*)d_in[4];
  const float* R2 = (const float*)d_in[5];
  const float* b2 = (const float*)d_in[6];
  const float* W3 = (const float*)d_in[7];
  const float* R3 = (const float*)d_in[8];
  const float* b3 = (const float*)d_in[9];
  char* ws = (char*)d_ws;
  ushort_t* xbf = (ushort_t*)(ws + OFF_XBF);
  ushort_t* W1t = (ushort_t*)(ws + OFF_W1T);
  ushort_t* R1t = (ushort_t*)(ws + OFF_R1T);
  ushort_t* W2t = (ushort_t*)(ws + OFF_W2T);
  ushort_t* R2t = (ushort_t*)(ws + OFF_R2T);
  ushort_t* W3t = (ushort_t*)(ws + OFF_W3T);
  ushort_t* R3t = (ushort_t*)(ws + OFF_R3T);
  ushort_t* h1r = (ushort_t*)(ws + OFF_H1R);
  ushort_t* h2r = (ushort_t*)(ws + OFF_H2R);
  ushort_t* h3r = (ushort_t*)(ws + OFF_H3R);
  uint_t* cntp  = (uint_t*)(ws + OFF_CNT);

  k_cvtx<<<8192, 256, 0, stream>>>(x, xbf);
  k_tr<<<768, 256, 0, stream>>>(W1, W1t, 128, 1536, 196608);
  k_tr<<<3072, 256, 0, stream>>>(R1, R1t, 512, 1536, 786432);
  k_tr<<<3072, 256, 0, stream>>>(W2, W2t, 512, 1536, 786432);
  k_tr<<<3072, 256, 0, stream>>>(R2, R2t, 512, 1536, 786432);
  k_tr<<<384, 256, 0, stream>>>(W3, W3t, 512, 192, 98304);
  k_tr<<<48, 256, 0, stream>>>(R3, R3t, 64, 192, 12288);
  k_zero<<<545, 256, 0, stream>>>((uint_t*)(ws + OFF_H1R), (uint_t*)(ws + OFF_H2R),
                                  (uint_t*)(ws + OFF_H3R), (uint_t*)(ws + OFF_CNT));
  gru_main<<<256, 256, 0, stream>>>(xbf, W1t, R1t, W2t, R2t, W3t, R3t,
                                    b1, b2, b3, h1r, h2r, h3r, cntp, (float*)d_out);
}

// Round 2
// 5739.503 us; speedup vs baseline: 2.9044x; 2.9044x over previous
//
#include <hip/hip_runtime.h>

typedef unsigned short ushort_t;
typedef unsigned int uint_t;
typedef __attribute__((ext_vector_type(8))) short short8;
typedef __attribute__((ext_vector_type(4))) float f32x4;

#define MFMA16(a, b, c) __builtin_amdgcn_mfma_f32_16x16x32_bf16((a), (b), (c), 0, 0, 0)

__device__ __forceinline__ ushort_t f2bf(float f) {
  union { float f; uint_t u; } v; v.f = f;
  uint_t r = v.u + 0x7fffu + ((v.u >> 16) & 1u);
  return (ushort_t)(r >> 16);
}
__device__ __forceinline__ float sigm(float x) { return 1.f / (1.f + __expf(-x)); }

// Device-coherent 16B fragment load (two 8B relaxed agent atomics -> sc0|sc1,
// bypasses potentially-stale L1/L2; served from the coherence point).
__device__ __forceinline__ short8 ldc(const ushort_t* p) {
  union { unsigned long long q[2]; short8 v; } u;
  u.q[0] = __hip_atomic_load((const unsigned long long*)p, __ATOMIC_RELAXED,
                             __HIP_MEMORY_SCOPE_AGENT);
  u.q[1] = __hip_atomic_load((const unsigned long long*)(p + 4), __ATOMIC_RELAXED,
                             __HIP_MEMORY_SCOPE_AGENT);
  return u.v;
}

// ---------------- workspace layout (bytes) ----------------
#define OFF_XBF  0UL            // bf16 x^T     [256][256][128] (T,B,D)  16777216
#define OFF_W1T  16777216UL     // bf16 W1^T    [1536][128]      393216
#define OFF_R1T  17170432UL     // bf16 R1^T    [1536][512]      1572864
#define OFF_W2T  18743296UL     // bf16 W2^T    [1536][512]      1572864
#define OFF_R2T  20316160UL     // bf16 R2^T    [1536][512]      1572864
#define OFF_W3T  21889024UL     // bf16 W3^T    [192][512]       196608
#define OFF_R3T  22085632UL     // bf16 R3^T    [192][64]        24576
#define OFF_H1R  22110208UL     // bf16 ring    [4][256][512]    1048576
#define OFF_H2R  23158784UL     // bf16 ring    [4][256][512]    1048576
#define OFF_H3R  24207360UL     // bf16 ring    [4][256][64]     131072
#define OFF_CNT  24338432UL     // uint cnt[64] (chain*16)       256

// ---------------- init kernels ----------------
// x [B][T][D] fp32 -> xb [T][B][D] bf16 (transpose so layer1 reads are contiguous)
__global__ void k_cvtx(const float* __restrict__ x, ushort_t* __restrict__ xb) {
  const int i = blockIdx.x * 256 + threadIdx.x;   // over 2M float4 groups
  const int d4 = i & 31;
  const int t = (i >> 5) & 255;
  const int b = i >> 13;
  const float4 v = ((const float4*)x)[i];
  ushort4 o;
  o.x = f2bf(v.x); o.y = f2bf(v.y); o.z = f2bf(v.z); o.w = f2bf(v.w);
  ((ushort4*)xb)[(((t << 8) + b) << 5) + d4] = o;
}

// src [K][G] fp32 -> dst [G][K] bf16
__global__ void k_tr(const float* __restrict__ src, ushort_t* __restrict__ dst,
                     int K, int G, int n) {
  const int i = blockIdx.x * 256 + threadIdx.x;
  if (i >= n) return;
  const int g = i / K, k = i - g * K;
  dst[i] = f2bf(src[(size_t)k * G + g]);
}

__global__ void k_zero(uint_t* h1, uint_t* h2, uint_t* h3, uint_t* cnt) {
  const int i = blockIdx.x * 256 + threadIdx.x;
  if (i < 65536) h1[196608 + i] = 0;                    // h1 ring slot 3
  else if (i < 131072) h2[196608 + (i - 65536)] = 0;    // h2 ring slot 3
  else if (i < 139264) h3[24576 + (i - 131072)] = 0;    // h3 ring slot 3
  else if (i < 139328) cnt[i - 139264] = 0;             // chain counters
}

// ---------------- persistent pipelined GRU ----------------
// grid = 256 blocks x 256 threads. chain = (bid&7)>>1 (64 WGs/chain).
// member<32 -> layer1 colgroup, else layer2 colgroup; layer1 cg 28..31 also layer3.
// Superstep s: layer1 t=s, layer2 t=s-1, layer3 t=s-2. One chain barrier/step.
// Cross-WG data: plain stores (pushed to coherence point by the RELEASE fetch_add's
// buffer_wbl2), read back with sc0|sc1 relaxed atomic loads (ldc). NO acquire /
// threadfence anywhere in the loop -> no L2 invalidates (R1's 64us/step pathology).
__global__ __launch_bounds__(256, 1)
void gru_main(const ushort_t* __restrict__ xbf,
              const ushort_t* __restrict__ W1t, const ushort_t* __restrict__ R1t,
              const ushort_t* __restrict__ W2t, const ushort_t* __restrict__ R2t,
              const ushort_t* __restrict__ W3t, const ushort_t* __restrict__ R3t,
              const float* __restrict__ b1, const float* __restrict__ b2,
              const float* __restrict__ b3,
              ushort_t* __restrict__ h1r, ushort_t* __restrict__ h2r,
              ushort_t* __restrict__ h3r,
              uint_t* __restrict__ cnt, float* __restrict__ out) {
  __shared__ ushort_t smem[31488];
  const int tid = threadIdx.x;
  const int bid = blockIdx.x;
  const int xcd = bid & 7;
  const int slot = bid >> 3;
  const int chain = xcd >> 1;
  const int member = ((xcd & 1) << 5) | slot;   // 0..63
  const bool isL1 = (member < 32);
  const int cg = isL1 ? member : (member - 32);
  const bool isL3 = isL1 && (cg >= 28);
  const int cg3 = cg - 28;
  const int b0 = chain << 6;
  const int lane = tid & 63;
  const int wid = tid >> 6;
  const int l15 = lane & 15;
  const int quad = lane >> 4;
  const int m0 = wid << 4;
  const int ucol = (cg << 4) + l15;
  const int u3col = (cg3 << 4) + l15;

  // ---- stage weight slices to LDS ----
  if (isL1) {
    for (int i = tid; i < 3072; i += 256) {
      const int dr = i >> 6, dc = (i & 63) << 3;
      const int g = ((dr >> 4) << 9) + (cg << 4) + (dr & 15);
      *(short8*)&smem[dr * 520 + dc] = *(const short8*)&R1t[(size_t)g * 512 + dc];
    }
    for (int i = tid; i < 768; i += 256) {
      const int dr = i >> 4, dc = (i & 15) << 3;
      const int g = ((dr >> 4) << 9) + (cg << 4) + (dr & 15);
      *(short8*)&smem[24960 + dr * 136 + dc] = *(const short8*)&W1t[(size_t)g * 128 + dc];
    }
  } else {
    for (int i = tid; i < 3072; i += 256) {
      const int dr = i >> 6, dc = (i & 63) << 3;
      const int g = ((dr >> 4) << 9) + (cg << 4) + (dr & 15);
      *(short8*)&smem[dr * 520 + dc] = *(const short8*)&R2t[(size_t)g * 512 + dc];
    }
  }

  float bz0, brr0, bh0, bz1, brr1, bh1;
  {
    const float* bb = isL1 ? b1 : b2;
    bz0 = bb[ucol];        brr0 = bb[512 + ucol];  bh0 = bb[1024 + ucol];
    bz1 = bb[1536 + ucol]; brr1 = bb[2048 + ucol]; bh1 = bb[2560 + ucol];
  }
  float cz0 = 0, cr0 = 0, ch0 = 0, cz1 = 0, cr1 = 0, ch1 = 0;
  if (isL3) {
    cz0 = b3[u3col];       cr0 = b3[64 + u3col];   ch0 = b3[128 + u3col];
    cz1 = b3[192 + u3col]; cr1 = b3[256 + u3col];  ch1 = b3[320 + u3col];
  }

  const int kh = wid & 1, mh = wid >> 1;
  short8 w2f[3][8];
  if (!isL1) {
#pragma unroll
    for (int nt = 0; nt < 3; ++nt)
#pragma unroll
      for (int k = 0; k < 8; ++k)
        w2f[nt][k] = *(const short8*)&W2t[(size_t)((nt << 9) + ucol) * 512 +
                                          (((kh << 3) + k) << 5) + (quad << 3)];
  }
  __syncthreads();

  float hOwn1[4] = {0, 0, 0, 0};
  float hOwn2[8] = {0, 0, 0, 0, 0, 0, 0, 0};
  float hOwn3[4] = {0, 0, 0, 0};
  float* scr = (float*)&smem[24960];
  const f32x4 zero4 = {0.f, 0.f, 0.f, 0.f};

  for (int s = 0; s < 258; ++s) {
    if (isL1) {
      if (s < 256) {
        f32x4 ax[3] = {zero4, zero4, zero4};
        f32x4 ar[3] = {zero4, zero4, zero4};
        // xp1 = x[t=s] @ W1slice (K=128); x^T layout -> contiguous 16KB/chain-step
        const ushort_t* xr = xbf + (((size_t)s << 8) + (b0 + m0 + l15)) * 128;
#pragma unroll
        for (int kk = 0; kk < 4; ++kk) {
          const short8 a = *(const short8*)&xr[(kk << 5) + (quad << 3)];
#pragma unroll
          for (int nt = 0; nt < 3; ++nt) {
            const short8 b = *(const short8*)&smem[24960 + ((nt << 4) + l15) * 136 +
                                                   (kk << 5) + (quad << 3)];
            ax[nt] = MFMA16(a, b, ax[nt]);
          }
        }
        // rec = h1_{s-1} @ R1slice (K=512), device-coherent ring read
        const ushort_t* hr =
            h1r + (((size_t)((s - 1) & 3)) * 256 + (b0 + m0 + l15)) * 512;
#pragma unroll
        for (int kk = 0; kk < 16; ++kk) {
          const short8 a = ldc(&hr[(kk << 5) + (quad << 3)]);
#pragma unroll
          for (int nt = 0; nt < 3; ++nt) {
            const short8 b =
                *(const short8*)&smem[((nt << 4) + l15) * 520 + (kk << 5) + (quad << 3)];
            ar[nt] = MFMA16(a, b, ar[nt]);
          }
        }
        const int wslot = s & 3;
#pragma unroll
        for (int r = 0; r < 4; ++r) {
          const float z = sigm(ax[0][r] + bz0 + ar[0][r] + bz1);
          const float rg = sigm(ax[1][r] + brr0 + ar[1][r] + brr1);
          const float hh = fmaxf(ax[2][r] + bh0 + rg * (ar[2][r] + bh1), 0.f);
          const float hn = z * hOwn1[r] + (1.f - z) * hh;
          hOwn1[r] = hn;
          const int row = b0 + m0 + (quad << 2) + r;
          h1r[((size_t)wslot * 256 + row) * 512 + ucol] = f2bf(hn);
        }
      }
      if (isL3 && s >= 2) {
        const int t3 = s - 2;
        f32x4 qx[3] = {zero4, zero4, zero4};
        f32x4 qr[3] = {zero4, zero4, zero4};
        const ushort_t* h2row =
            h2r + (((size_t)((s - 2) & 3)) * 256 + (b0 + m0 + l15)) * 512;
#pragma unroll
        for (int kk = 0; kk < 16; ++kk) {
          const short8 a = ldc(&h2row[(kk << 5) + (quad << 3)]);
#pragma unroll
          for (int nt = 0; nt < 3; ++nt) {
            const short8 b = *(const short8*)&W3t[(size_t)((nt << 6) + u3col) * 512 +
                                                  (kk << 5) + (quad << 3)];
            qx[nt] = MFMA16(a, b, qx[nt]);
          }
        }
        const ushort_t* h3row =
            h3r + (((size_t)((s - 3) & 3)) * 256 + (b0 + m0 + l15)) * 64;
#pragma unroll
        for (int kk = 0; kk < 2; ++kk) {
          const short8 a = ldc(&h3row[(kk << 5) + (quad << 3)]);
#pragma unroll
          for (int nt = 0; nt < 3; ++nt) {
            const short8 b = *(const short8*)&R3t[(size_t)((nt << 6) + u3col) * 64 +
                                                  (kk << 5) + (quad << 3)];
            qr[nt] = MFMA16(a, b, qr[nt]);
          }
        }
        const int w3 = (s - 2) & 3;
#pragma unroll
        for (int r = 0; r < 4; ++r) {
          const float z = sigm(qx[0][r] + cz0 + qr[0][r] + cz1);
          const float rg = sigm(qx[1][r] + cr0 + qr[1][r] + cr1);
          const float hh = sigm(qx[2][r] + ch0 + rg * (qr[2][r] + ch1));
          const float hn = z * hOwn3[r] + (1.f - z) * hh;
          hOwn3[r] = hn;
          const int row = b0 + m0 + (quad << 2) + r;
          h3r[((size_t)w3 * 256 + row) * 64 + u3col] = f2bf(hn);
          out[((size_t)row * 256 + t3) * 64 + u3col] = hn;
        }
      }
    } else {
      if (s >= 1 && s < 257) {
        f32x4 px[6] = {zero4, zero4, zero4, zero4, zero4, zero4};
        f32x4 pr[6] = {zero4, zero4, zero4, zero4, zero4, zero4};
        const size_t hxb = ((size_t)((s - 1) & 3)) * 256;
        const size_t hrb = ((size_t)((s - 2) & 3)) * 256;
        const ushort_t* h1p[2];
        const ushort_t* h2p[2];
#pragma unroll
        for (int mt2 = 0; mt2 < 2; ++mt2) {
          const int mrow = b0 + (((mh << 1) + mt2) << 4) + l15;
          h1p[mt2] = h1r + (hxb + mrow) * 512;
          h2p[mt2] = h2r + (hrb + mrow) * 512;
        }
#pragma unroll
        for (int k = 0; k < 8; ++k) {
          const int koff = (((kh << 3) + k) << 5) + (quad << 3);
          short8 brg[3];
#pragma unroll
          for (int nt = 0; nt < 3; ++nt)
            brg[nt] = *(const short8*)&smem[((nt << 4) + l15) * 520 + koff];
#pragma unroll
          for (int mt2 = 0; mt2 < 2; ++mt2) {
            const short8 a1 = ldc(&h1p[mt2][koff]);
            const short8 a2 = ldc(&h2p[mt2][koff]);
#pragma unroll
            for (int nt = 0; nt < 3; ++nt) {
              px[mt2 * 3 + nt] = MFMA16(a1, w2f[nt][k], px[mt2 * 3 + nt]);
              pr[mt2 * 3 + nt] = MFMA16(a2, brg[nt], pr[mt2 * 3 + nt]);
            }
          }
        }
        __syncthreads();
        if (kh == 1) {
#pragma unroll
          for (int t = 0; t < 6; ++t)
            *(f32x4*)&scr[(((mh * 6 + t) << 6) + lane) << 2] = pr[t];
        }
        __syncthreads();
        if (kh == 0) {
#pragma unroll
          for (int t = 0; t < 6; ++t)
            pr[t] += *(const f32x4*)&scr[(((mh * 6 + t) << 6) + lane) << 2];
        }
        __syncthreads();
        if (kh == 1) {
#pragma unroll
          for (int t = 0; t < 6; ++t)
            *(f32x4*)&scr[(((mh * 6 + t) << 6) + lane) << 2] = px[t];
        }
        __syncthreads();
        if (kh == 0) {
          const int wslot = (s - 1) & 3;
#pragma unroll
          for (int t = 0; t < 6; ++t)
            px[t] += *(const f32x4*)&scr[(((mh * 6 + t) << 6) + lane) << 2];
#pragma unroll
          for (int mt2 = 0; mt2 < 2; ++mt2) {
#pragma unroll
            for (int r = 0; r < 4; ++r) {
              const int t0 = mt2 * 3;
              const float z = sigm(px[t0][r] + bz0 + pr[t0][r] + bz1);
              const float rg = sigm(px[t0 + 1][r] + brr0 + pr[t0 + 1][r] + brr1);
              const float hh =
                  fmaxf(px[t0 + 2][r] + bh0 + rg * (pr[t0 + 2][r] + bh1), 0.f);
              const float hn = z * hOwn2[mt2 * 4 + r] + (1.f - z) * hh;
              hOwn2[mt2 * 4 + r] = hn;
              const int row = b0 + (((mh << 1) + mt2) << 4) + (quad << 2) + r;
              h2r[((size_t)wslot * 256 + row) * 512 + ucol] = f2bf(hn);
            }
          }
        }
      }
    }
    // ---- chain barrier: release RMW (one wbl2/WG/step), RELAXED spin (no inv) ----
    __syncthreads();
    if (tid == 0) {
      __hip_atomic_fetch_add(&cnt[chain << 4], 1u, __ATOMIC_RELEASE,
                             __HIP_MEMORY_SCOPE_AGENT);
      const uint_t tgt = (uint_t)(s + 1) * 64u;
      while (__hip_atomic_load(&cnt[chain << 4], __ATOMIC_RELAXED,
                               __HIP_MEMORY_SCOPE_AGENT) < tgt) {
        __builtin_amdgcn_s_sleep(2);
      }
    }
    __syncthreads();
  }
}

extern "C" void kernel_launch(void* const* d_in, const int* in_sizes, int n_in,
                              void* d_out, int out_size, void* d_ws, size_t ws_size,
                              hipStream_t stream) {
  const float* x  = (const float*)d_in[0];
  const float* W1 = (const float*)d_in[1];
  const float* R1 = (const float*)d_in[2];
  const float* b1 = (const float*)d_in[3];
  const float* W2 = (const float*)d_in[4];
  const float* R2 = (const float*)d_in[5];
  const float* b2 = (const float*)d_in[6];
  const float* W3 = (const float*)d_in[7];
  const float* R3 = (const float*)d_in[8];
  const float* b3 = (const float*)d_in[9];
  char* ws = (char*)d_ws;
  ushort_t* xbf = (ushort_t*)(ws + OFF_XBF);
  ushort_t* W1t = (ushort_t*)(ws + OFF_W1T);
  ushort_t* R1t = (ushort_t*)(ws + OFF_R1T);
  ushort_t* W2t = (ushort_t*)(ws + OFF_W2T);
  ushort_t* R2t = (ushort_t*)(ws + OFF_R2T);
  ushort_t* W3t = (ushort_t*)(ws + OFF_W3T);
  ushort_t* R3t = (ushort_t*)(ws + OFF_R3T);
  ushort_t* h1r = (ushort_t*)(ws + OFF_H1R);
  ushort_t* h2r = (ushort_t*)(ws + OFF_H2R);
  ushort_t* h3r = (ushort_t*)(ws + OFF_H3R);
  uint_t* cntp  = (uint_t*)(ws + OFF_CNT);

  k_cvtx<<<8192, 256, 0, stream>>>(x, xbf);
  k_tr<<<768, 256, 0, stream>>>(W1, W1t, 128, 1536, 196608);
  k_tr<<<3072, 256, 0, stream>>>(R1, R1t, 512, 1536, 786432);
  k_tr<<<3072, 256, 0, stream>>>(W2, W2t, 512, 1536, 786432);
  k_tr<<<3072, 256, 0, stream>>>(R2, R2t, 512, 1536, 786432);
  k_tr<<<384, 256, 0, stream>>>(W3, W3t, 512, 192, 98304);
  k_tr<<<48, 256, 0, stream>>>(R3, R3t, 64, 192, 12288);
  k_zero<<<545, 256, 0, stream>>>((uint_t*)(ws + OFF_H1R), (uint_t*)(ws + OFF_H2R),
                                  (uint_t*)(ws + OFF_H3R), (uint_t*)(ws + OFF_CNT));
  gru_main<<<256, 256, 0, stream>>>(xbf, W1t, R1t, W2t, R2t, W3t, R3t,
                                    b1, b2, b3, h1r, h2r, h3r, cntp, (float*)d_out);
}

// Round 3
// 3895.890 us; speedup vs baseline: 4.2788x; 1.4732x over previous
//
#include <hip/hip_runtime.h>

typedef unsigned short ushort_t;
typedef unsigned int uint_t;
typedef __attribute__((ext_vector_type(8))) short short8;
typedef __attribute__((ext_vector_type(4))) float f32x4;

#define MFMA16(a, b, c) __builtin_amdgcn_mfma_f32_16x16x32_bf16((a), (b), (c), 0, 0, 0)

__device__ __forceinline__ ushort_t f2bf(float f) {
  union { float f; uint_t u; } v; v.f = f;
  uint_t r = v.u + 0x7fffu + ((v.u >> 16) & 1u);
  return (ushort_t)(r >> 16);
}
__device__ __forceinline__ float sigm(float x) { return 1.f / (1.f + __expf(-x)); }

// Device-coherent 16B fragment load (two 8B relaxed agent atomics, bypasses
// stale L1/L2). Used only in RING fallback mode where addresses are reused.
__device__ __forceinline__ short8 ldc(const ushort_t* p) {
  union { unsigned long long q[2]; short8 v; } u;
  u.q[0] = __hip_atomic_load((const unsigned long long*)p, __ATOMIC_RELAXED,
                             __HIP_MEMORY_SCOPE_AGENT);
  u.q[1] = __hip_atomic_load((const unsigned long long*)(p + 4), __ATOMIC_RELAXED,
                             __HIP_MEMORY_SCOPE_AGENT);
  return u.v;
}

// Mode-dependent fragment load. SEQ mode: addresses are written exactly once
// before being read (monotonic slots) and caches start invalidated at dispatch
// -> plain cached 16B load is coherent. RING mode: must bypass caches.
template <bool SEQ>
__device__ __forceinline__ short8 ldfrag(const ushort_t* p) {
  if constexpr (SEQ) return *(const short8*)p;
  else return ldc(p);
}

// Write-through 2B store (agent-scope relaxed atomic store -> sc0|sc1):
// lands at the coherence point without needing any wbl2 at the barrier.
__device__ __forceinline__ void stc(ushort_t* p, ushort_t v) {
  __hip_atomic_store(p, v, __ATOMIC_RELAXED, __HIP_MEMORY_SCOPE_AGENT);
}

// ---------------- workspace layout (bytes) ----------------
// common prefix
#define OFF_XBF  0UL            // bf16 x^T [256][256][128] (T,B,D)  16777216
#define OFF_W1T  16777216UL     // bf16 W1^T [1536][128]   393216
#define OFF_R1T  17170432UL     // bf16 R1^T [1536][512]   1572864
#define OFF_W2T  18743296UL     // bf16 W2^T [1536][512]   1572864
#define OFF_R2T  20316160UL     // bf16 R2^T [1536][512]   1572864
#define OFF_W3T  21889024UL     // bf16 W3^T [192][512]    196608
#define OFF_R3T  22085632UL     // bf16 R3^T [192][64]     24576
#define OFF_CNT  22110208UL     // uint cnt  (4096B)
#define OFF_H    22114304UL     // h buffers start here
// SEQ mode: h1 [257][256][512], h2 [257][256][512], h3 [257][256][64] bf16
#define H1_BYTES_SEQ  (257UL * 262144UL)   // 67371008
#define H3_BYTES_SEQ  (257UL * 32768UL)    // 8421376
#define SEQ_NEED (OFF_H + 2UL * H1_BYTES_SEQ + H3_BYTES_SEQ)  // 165277696
// RING mode: depth-4 slots
#define H1_BYTES_RING (4UL * 262144UL)
#define H3_BYTES_RING (4UL * 32768UL)

// ---------------- init kernels ----------------
// x [B][T][D] fp32 -> xb [T][B][D] bf16
__global__ void k_cvtx(const float* __restrict__ x, ushort_t* __restrict__ xb) {
  const int i = blockIdx.x * 256 + threadIdx.x;
  const int d4 = i & 31;
  const int t = (i >> 5) & 255;
  const int b = i >> 13;
  const float4 v = ((const float4*)x)[i];
  ushort4 o;
  o.x = f2bf(v.x); o.y = f2bf(v.y); o.z = f2bf(v.z); o.w = f2bf(v.w);
  ((ushort4*)xb)[(((t << 8) + b) << 5) + d4] = o;
}

// src [K][G] fp32 -> dst [G][K] bf16
__global__ void k_tr(const float* __restrict__ src, ushort_t* __restrict__ dst,
                     int K, int G, int n) {
  const int i = blockIdx.x * 256 + threadIdx.x;
  if (i >= n) return;
  const int g = i / K, k = i - g * K;
  dst[i] = f2bf(src[(size_t)k * G + g]);
}

// zero slot 0 of each h buffer (h[-1] = 0) + chain counters
__global__ void k_zero(uint_t* h1, uint_t* h2, uint_t* h3, uint_t* cnt) {
  const int i = blockIdx.x * 256 + threadIdx.x;
  if (i < 65536) h1[i] = 0;
  else if (i < 131072) h2[i - 65536] = 0;
  else if (i < 139264) h3[i - 131072] = 0;
  else if (i < 139328) cnt[i - 139264] = 0;
}

// ---------------- persistent pipelined GRU ----------------
// grid = 256 x 256. chain = (bid&7)>>1 (64 WGs, one XCD pair). member<32 ->
// layer1 colgroup, else layer2 colgroup; layer1 cg 28..31 also layer3.
// Superstep s: layer1 t=s, layer2 t=s-1, layer3 t=s-2. One chain barrier/step.
// Slot convention: h*[t] lives in slot t+1 (slot0 = zeros). SEQ: slot index is
// exact (monotonic, never reused -> plain cached reads). RING: slot & 3 with
// sc0|sc1 reads. Stores are write-through (stc) in both modes; barrier RMW is
// RELAXED -> no wbl2 / no inv anywhere in the hot loop.
template <bool SEQ>
__global__ __launch_bounds__(256, 1)
void gru_main(const ushort_t* __restrict__ xbf,
              const ushort_t* __restrict__ W1t, const ushort_t* __restrict__ R1t,
              const ushort_t* __restrict__ W2t, const ushort_t* __restrict__ R2t,
              const ushort_t* __restrict__ W3t, const ushort_t* __restrict__ R3t,
              const float* __restrict__ b1, const float* __restrict__ b2,
              const float* __restrict__ b3,
              ushort_t* __restrict__ h1s, ushort_t* __restrict__ h2s,
              ushort_t* __restrict__ h3s,
              uint_t* __restrict__ cnt, float* __restrict__ out) {
  __shared__ ushort_t smem[31488];
  const int tid = threadIdx.x;
  const int bid = blockIdx.x;
  const int xcd = bid & 7;
  const int slot = bid >> 3;
  const int chain = xcd >> 1;
  const int member = ((xcd & 1) << 5) | slot;   // 0..63
  const bool isL1 = (member < 32);
  const int cg = isL1 ? member : (member - 32);
  const bool isL3 = isL1 && (cg >= 28);
  const int cg3 = cg - 28;
  const int b0 = chain << 6;
  const int lane = tid & 63;
  const int wid = tid >> 6;
  const int l15 = lane & 15;
  const int quad = lane >> 4;
  const int m0 = wid << 4;
  const int ucol = (cg << 4) + l15;
  const int u3col = (cg3 << 4) + l15;

  // ---- stage weight slices to LDS ----
  if (isL1) {
    for (int i = tid; i < 3072; i += 256) {
      const int dr = i >> 6, dc = (i & 63) << 3;
      const int g = ((dr >> 4) << 9) + (cg << 4) + (dr & 15);
      *(short8*)&smem[dr * 520 + dc] = *(const short8*)&R1t[(size_t)g * 512 + dc];
    }
    for (int i = tid; i < 768; i += 256) {
      const int dr = i >> 4, dc = (i & 15) << 3;
      const int g = ((dr >> 4) << 9) + (cg << 4) + (dr & 15);
      *(short8*)&smem[24960 + dr * 136 + dc] = *(const short8*)&W1t[(size_t)g * 128 + dc];
    }
  } else {
    for (int i = tid; i < 3072; i += 256) {
      const int dr = i >> 6, dc = (i & 63) << 3;
      const int g = ((dr >> 4) << 9) + (cg << 4) + (dr & 15);
      *(short8*)&smem[dr * 520 + dc] = *(const short8*)&R2t[(size_t)g * 512 + dc];
    }
  }

  float bz0, brr0, bh0, bz1, brr1, bh1;
  {
    const float* bb = isL1 ? b1 : b2;
    bz0 = bb[ucol];        brr0 = bb[512 + ucol];  bh0 = bb[1024 + ucol];
    bz1 = bb[1536 + ucol]; brr1 = bb[2048 + ucol]; bh1 = bb[2560 + ucol];
  }
  float cz0 = 0, cr0 = 0, ch0 = 0, cz1 = 0, cr1 = 0, ch1 = 0;
  if (isL3) {
    cz0 = b3[u3col];       cr0 = b3[64 + u3col];   ch0 = b3[128 + u3col];
    cz1 = b3[192 + u3col]; cr1 = b3[256 + u3col];  ch1 = b3[320 + u3col];
  }

  const int kh = wid & 1, mh = wid >> 1;
  short8 w2f[3][8];
  if (!isL1) {
#pragma unroll
    for (int nt = 0; nt < 3; ++nt)
#pragma unroll
      for (int k = 0; k < 8; ++k)
        w2f[nt][k] = *(const short8*)&W2t[(size_t)((nt << 9) + ucol) * 512 +
                                          (((kh << 3) + k) << 5) + (quad << 3)];
  }
  __syncthreads();

  float hOwn1[4] = {0, 0, 0, 0};
  float hOwn2[8] = {0, 0, 0, 0, 0, 0, 0, 0};
  float hOwn3[4] = {0, 0, 0, 0};
  float* scr = (float*)&smem[24960];
  const f32x4 zero4 = {0.f, 0.f, 0.f, 0.f};

  for (int s = 0; s < 258; ++s) {
    if (isL1) {
      if (s < 256) {
        f32x4 ax[3] = {zero4, zero4, zero4};
        f32x4 ar[3] = {zero4, zero4, zero4};
        const ushort_t* xr = xbf + (((size_t)s << 8) + (b0 + m0 + l15)) * 128;
#pragma unroll
        for (int kk = 0; kk < 4; ++kk) {
          const short8 a = *(const short8*)&xr[(kk << 5) + (quad << 3)];
#pragma unroll
          for (int nt = 0; nt < 3; ++nt) {
            const short8 b = *(const short8*)&smem[24960 + ((nt << 4) + l15) * 136 +
                                                   (kk << 5) + (quad << 3)];
            ax[nt] = MFMA16(a, b, ax[nt]);
          }
        }
        // rec = h1[s-1] @ R1slice: h1 slot s
        const ushort_t* hr =
            h1s + ((size_t)(SEQ ? s : (s & 3)) * 131072) + (size_t)(b0 + m0 + l15) * 512;
#pragma unroll
        for (int kk = 0; kk < 16; ++kk) {
          const short8 a = ldfrag<SEQ>(&hr[(kk << 5) + (quad << 3)]);
#pragma unroll
          for (int nt = 0; nt < 3; ++nt) {
            const short8 b =
                *(const short8*)&smem[((nt << 4) + l15) * 520 + (kk << 5) + (quad << 3)];
            ar[nt] = MFMA16(a, b, ar[nt]);
          }
        }
        const int wsl = SEQ ? (s + 1) : ((s + 1) & 3);
#pragma unroll
        for (int r = 0; r < 4; ++r) {
          const float z = sigm(ax[0][r] + bz0 + ar[0][r] + bz1);
          const float rg = sigm(ax[1][r] + brr0 + ar[1][r] + brr1);
          const float hh = fmaxf(ax[2][r] + bh0 + rg * (ar[2][r] + bh1), 0.f);
          const float hn = z * hOwn1[r] + (1.f - z) * hh;
          hOwn1[r] = hn;
          const int row = b0 + m0 + (quad << 2) + r;
          stc(&h1s[(size_t)wsl * 131072 + (size_t)row * 512 + ucol], f2bf(hn));
        }
      }
      if (isL3 && s >= 2) {
        const int t3 = s - 2;
        f32x4 qx[3] = {zero4, zero4, zero4};
        f32x4 qr[3] = {zero4, zero4, zero4};
        // h2[t3] = slot s-1
        const ushort_t* h2row =
            h2s + ((size_t)(SEQ ? (s - 1) : ((s - 1) & 3)) * 131072) +
            (size_t)(b0 + m0 + l15) * 512;
#pragma unroll
        for (int kk = 0; kk < 16; ++kk) {
          const short8 a = ldfrag<SEQ>(&h2row[(kk << 5) + (quad << 3)]);
#pragma unroll
          for (int nt = 0; nt < 3; ++nt) {
            const short8 b = *(const short8*)&W3t[(size_t)((nt << 6) + u3col) * 512 +
                                                  (kk << 5) + (quad << 3)];
            qx[nt] = MFMA16(a, b, qx[nt]);
          }
        }
        // h3[t3-1] = slot s-2
        const ushort_t* h3row =
            h3s + ((size_t)(SEQ ? (s - 2) : ((s - 2) & 3)) * 16384) +
            (size_t)(b0 + m0 + l15) * 64;
#pragma unroll
        for (int kk = 0; kk < 2; ++kk) {
          const short8 a = ldfrag<SEQ>(&h3row[(kk << 5) + (quad << 3)]);
#pragma unroll
          for (int nt = 0; nt < 3; ++nt) {
            const short8 b = *(const short8*)&R3t[(size_t)((nt << 6) + u3col) * 64 +
                                                  (kk << 5) + (quad << 3)];
            qr[nt] = MFMA16(a, b, qr[nt]);
          }
        }
        const int w3 = SEQ ? (s - 1) : ((s - 1) & 3);
#pragma unroll
        for (int r = 0; r < 4; ++r) {
          const float z = sigm(qx[0][r] + cz0 + qr[0][r] + cz1);
          const float rg = sigm(qx[1][r] + cr0 + qr[1][r] + cr1);
          const float hh = sigm(qx[2][r] + ch0 + rg * (qr[2][r] + ch1));
          const float hn = z * hOwn3[r] + (1.f - z) * hh;
          hOwn3[r] = hn;
          const int row = b0 + m0 + (quad << 2) + r;
          stc(&h3s[(size_t)w3 * 16384 + (size_t)row * 64 + u3col], f2bf(hn));
          out[((size_t)row * 256 + t3) * 64 + u3col] = hn;
        }
      }
    } else {
      if (s >= 1 && s < 257) {
        f32x4 px[6] = {zero4, zero4, zero4, zero4, zero4, zero4};
        f32x4 pr[6] = {zero4, zero4, zero4, zero4, zero4, zero4};
        // h1[t2=s-1] = slot s ; h2[t2-1=s-2] = slot s-1
        const size_t hxb = (size_t)(SEQ ? s : (s & 3)) * 131072;
        const size_t hrb = (size_t)(SEQ ? (s - 1) : ((s - 1) & 3)) * 131072;
        const ushort_t* h1p[2];
        const ushort_t* h2p[2];
#pragma unroll
        for (int mt2 = 0; mt2 < 2; ++mt2) {
          const int mrow = b0 + (((mh << 1) + mt2) << 4) + l15;
          h1p[mt2] = h1s + hxb + (size_t)mrow * 512;
          h2p[mt2] = h2s + hrb + (size_t)mrow * 512;
        }
#pragma unroll
        for (int k = 0; k < 8; ++k) {
          const int koff = (((kh << 3) + k) << 5) + (quad << 3);
          short8 brg[3];
#pragma unroll
          for (int nt = 0; nt < 3; ++nt)
            brg[nt] = *(const short8*)&smem[((nt << 4) + l15) * 520 + koff];
#pragma unroll
          for (int mt2 = 0; mt2 < 2; ++mt2) {
            const short8 a1 = ldfrag<SEQ>(&h1p[mt2][koff]);
            const short8 a2 = ldfrag<SEQ>(&h2p[mt2][koff]);
#pragma unroll
            for (int nt = 0; nt < 3; ++nt) {
              px[mt2 * 3 + nt] = MFMA16(a1, w2f[nt][k], px[mt2 * 3 + nt]);
              pr[mt2 * 3 + nt] = MFMA16(a2, brg[nt], pr[mt2 * 3 + nt]);
            }
          }
        }
        __syncthreads();
        if (kh == 1) {
#pragma unroll
          for (int t = 0; t < 6; ++t)
            *(f32x4*)&scr[(((mh * 6 + t) << 6) + lane) << 2] = pr[t];
        }
        __syncthreads();
        if (kh == 0) {
#pragma unroll
          for (int t = 0; t < 6; ++t)
            pr[t] += *(const f32x4*)&scr[(((mh * 6 + t) << 6) + lane) << 2];
        }
        __syncthreads();
        if (kh == 1) {
#pragma unroll
          for (int t = 0; t < 6; ++t)
            *(f32x4*)&scr[(((mh * 6 + t) << 6) + lane) << 2] = px[t];
        }
        __syncthreads();
        if (kh == 0) {
          const int wsl = SEQ ? s : (s & 3);   // h2[s-1] -> slot s
#pragma unroll
          for (int t = 0; t < 6; ++t)
            px[t] += *(const f32x4*)&scr[(((mh * 6 + t) << 6) + lane) << 2];
#pragma unroll
          for (int mt2 = 0; mt2 < 2; ++mt2) {
#pragma unroll
            for (int r = 0; r < 4; ++r) {
              const int t0 = mt2 * 3;
              const float z = sigm(px[t0][r] + bz0 + pr[t0][r] + bz1);
              const float rg = sigm(px[t0 + 1][r] + brr0 + pr[t0 + 1][r] + brr1);
              const float hh =
                  fmaxf(px[t0 + 2][r] + bh0 + rg * (pr[t0 + 2][r] + bh1), 0.f);
              const float hn = z * hOwn2[mt2 * 4 + r] + (1.f - z) * hh;
              hOwn2[mt2 * 4 + r] = hn;
              const int row = b0 + (((mh << 1) + mt2) << 4) + (quad << 2) + r;
              stc(&h2s[(size_t)wsl * 131072 + (size_t)row * 512 + ucol], f2bf(hn));
            }
          }
        }
      }
    }
    // ---- chain barrier: all-relaxed (no wbl2, no inv). __syncthreads provides
    // vmcnt(0) so all write-through stores are at the coherence point before
    // the counter bump becomes visible. ----
    __syncthreads();
    if (tid == 0) {
      __hip_atomic_fetch_add(&cnt[chain << 4], 1u, __ATOMIC_RELAXED,
                             __HIP_MEMORY_SCOPE_AGENT);
      const uint_t tgt = (uint_t)(s + 1) * 64u;
      while (__hip_atomic_load(&cnt[chain << 4], __ATOMIC_RELAXED,
                               __HIP_MEMORY_SCOPE_AGENT) < tgt) {
        __builtin_amdgcn_s_sleep(2);
      }
    }
    __syncthreads();
  }
}

extern "C" void kernel_launch(void* const* d_in, const int* in_sizes, int n_in,
                              void* d_out, int out_size, void* d_ws, size_t ws_size,
                              hipStream_t stream) {
  const float* x  = (const float*)d_in[0];
  const float* W1 = (const float*)d_in[1];
  const float* R1 = (const float*)d_in[2];
  const float* b1 = (const float*)d_in[3];
  const float* W2 = (const float*)d_in[4];
  const float* R2 = (const float*)d_in[5];
  const float* b2 = (const float*)d_in[6];
  const float* W3 = (const float*)d_in[7];
  const float* R3 = (const float*)d_in[8];
  const float* b3 = (const float*)d_in[9];
  char* ws = (char*)d_ws;
  ushort_t* xbf = (ushort_t*)(ws + OFF_XBF);
  ushort_t* W1t = (ushort_t*)(ws + OFF_W1T);
  ushort_t* R1t = (ushort_t*)(ws + OFF_R1T);
  ushort_t* W2t = (ushort_t*)(ws + OFF_W2T);
  ushort_t* R2t = (ushort_t*)(ws + OFF_R2T);
  ushort_t* W3t = (ushort_t*)(ws + OFF_W3T);
  ushort_t* R3t = (ushort_t*)(ws + OFF_R3T);
  uint_t* cntp  = (uint_t*)(ws + OFF_CNT);

  const bool seq = (ws_size >= SEQ_NEED);
  ushort_t *h1p, *h2p, *h3p;
  if (seq) {
    h1p = (ushort_t*)(ws + OFF_H);
    h2p = (ushort_t*)(ws + OFF_H + H1_BYTES_SEQ);
    h3p = (ushort_t*)(ws + OFF_H + 2UL * H1_BYTES_SEQ);
  } else {
    h1p = (ushort_t*)(ws + OFF_H);
    h2p = (ushort_t*)(ws + OFF_H + H1_BYTES_RING);
    h3p = (ushort_t*)(ws + OFF_H + 2UL * H1_BYTES_RING);
  }

  k_cvtx<<<8192, 256, 0, stream>>>(x, xbf);
  k_tr<<<768, 256, 0, stream>>>(W1, W1t, 128, 1536, 196608);
  k_tr<<<3072, 256, 0, stream>>>(R1, R1t, 512, 1536, 786432);
  k_tr<<<3072, 256, 0, stream>>>(W2, W2t, 512, 1536, 786432);
  k_tr<<<3072, 256, 0, stream>>>(R2, R2t, 512, 1536, 786432);
  k_tr<<<384, 256, 0, stream>>>(W3, W3t, 512, 192, 98304);
  k_tr<<<48, 256, 0, stream>>>(R3, R3t, 64, 192, 12288);
  k_zero<<<545, 256, 0, stream>>>((uint_t*)h1p, (uint_t*)h2p, (uint_t*)h3p, cntp);
  if (seq) {
    gru_main<true><<<256, 256, 0, stream>>>(xbf, W1t, R1t, W2t, R2t, W3t, R3t,
                                            b1, b2, b3, h1p, h2p, h3p, cntp,
                                            (float*)d_out);
  } else {
    gru_main<false><<<256, 256, 0, stream>>>(xbf, W1t, R1t, W2t, R2t, W3t, R3t,
                                             b1, b2, b3, h1p, h2p, h3p, cntp,
                                             (float*)d_out);
  }
}

// Round 5
// 3662.784 us; speedup vs baseline: 4.5512x; 1.0636x over previous
//
#include <hip/hip_runtime.h>

typedef unsigned short ushort_t;
typedef unsigned int uint_t;
typedef unsigned long long ull_t;
typedef __attribute__((ext_vector_type(8))) short short8;
typedef __attribute__((ext_vector_type(4))) float f32x4;

#define MFMA16(a, b, c) __builtin_amdgcn_mfma_f32_16x16x32_bf16((a), (b), (c), 0, 0, 0)

__device__ __forceinline__ ushort_t f2bf(float f) {
  union { float f; uint_t u; } v; v.f = f;
  uint_t r = v.u + 0x7fffu + ((v.u >> 16) & 1u);
  return (ushort_t)(r >> 16);
}
__device__ __forceinline__ float sigm(float x) { return 1.f / (1.f + __expf(-x)); }

// Device-coherent 16B load (two 8B relaxed agent atomics). RING fallback only.
__device__ __forceinline__ short8 ldc(const ushort_t* p) {
  union { ull_t q[2]; short8 v; } u;
  u.q[0] = __hip_atomic_load((const ull_t*)p, __ATOMIC_RELAXED, __HIP_MEMORY_SCOPE_AGENT);
  u.q[1] = __hip_atomic_load((const ull_t*)(p + 4), __ATOMIC_RELAXED, __HIP_MEMORY_SCOPE_AGENT);
  return u.v;
}
template <bool SEQ>
__device__ __forceinline__ short8 ldh(const ushort_t* p) {
  if constexpr (SEQ) return *(const short8*)p;  // fresh (never-reused) address: cached load is coherent
  else return ldc(p);
}
// Write-through 8B store: lands at the device coherence point (no wbl2 needed).
__device__ __forceinline__ void stc8(ushort_t* p, ull_t v) {
  __hip_atomic_store((ull_t*)p, v, __ATOMIC_RELAXED, __HIP_MEMORY_SCOPE_AGENT);
}

// ---------------- workspace layout (bytes) ----------------
#define OFF_XBF  0UL            // bf16 x^T [256 t][256 b][128]  16777216
#define OFF_W1T  16777216UL     // bf16 W1^T [1536][128]   393216
#define OFF_R1T  17170432UL     // bf16 R1^T [1536][512]   1572864
#define OFF_W2T  18743296UL     // bf16 W2^T [1536][512]   1572864
#define OFF_R2T  20316160UL     // bf16 R2^T [1536][512]   1572864
#define OFF_W3T  21889024UL     // bf16 W3^T [192][512]    196608
#define OFF_R3T  22085632UL     // bf16 R3^T [192][64]     24576
#define OFF_CNT  22110208UL     // uint cnt[512]; chain c uses cnt[c*16]
#define OFF_H    22114304UL
// h1/h2 slot = [32 cg][256 row][16 col] ush = 131072 ush = 262144 B
// h3 slot    = [ 4 cg][256 row][16 col] ush =  16384 ush =  32768 B
#define H1_BYTES_SEQ  (257UL * 262144UL)
#define H3_BYTES_SEQ  (257UL * 32768UL)
#define SEQ_NEED (OFF_H + 2UL * H1_BYTES_SEQ + H3_BYTES_SEQ)
#define H1_BYTES_RING (4UL * 262144UL)

// ---------------- init kernels ----------------
__global__ void k_cvtx(const float* __restrict__ x, ushort_t* __restrict__ xb) {
  const int i = blockIdx.x * 256 + threadIdx.x;
  const int d4 = i & 31;
  const int t = (i >> 5) & 255;
  const int b = i >> 13;
  const float4 v = ((const float4*)x)[i];
  ushort4 o;
  o.x = f2bf(v.x); o.y = f2bf(v.y); o.z = f2bf(v.z); o.w = f2bf(v.w);
  ((ushort4*)xb)[(((t << 8) + b) << 5) + d4] = o;
}

__global__ void k_tr(const float* __restrict__ src, ushort_t* __restrict__ dst,
                     int K, int G, int n) {
  const int i = blockIdx.x * 256 + threadIdx.x;
  if (i >= n) return;
  const int g = i / K, k = i - g * K;
  dst[i] = f2bf(src[(size_t)k * G + g]);
}

__global__ void k_zero(uint_t* h1, uint_t* h2, uint_t* h3, uint_t* cnt) {
  const int i = blockIdx.x * 256 + threadIdx.x;
  if (i < 65536) h1[i] = 0;                    // h1 slot 0 (h1[-1]=0)
  else if (i < 131072) h2[i - 65536] = 0;      // h2 slot 0
  else if (i < 139264) h3[i - 131072] = 0;     // h3 slot 0
  else if (i < 139776) cnt[i - 139264] = 0;
}

// ---------------- persistent interleaved pipelined GRU ----------------
// 256 WGs x 256 thr. group = bid&7 (32 WGs); each group serves TWO chains of
// 16 batch rows (A: rows grp*32.., B: rows grp*32+16..), interleaved per
// superstep so each chain's barrier wait hides behind the other chain's
// compute. w = bid>>3 selects 16 u-cols (layers 1+2); w>=28 also runs layer3.
// Waves: lay = wid>>1 (0: L1+L3, 1: L2), sub = wid&1 (K-split halves).
// All weights register-resident (wreg union). h stored via LDS transpose as
// 8B write-through stores (full sectors); read with plain cached loads of
// monotonic SEQ addresses (R3-proven coherent). Barrier: relaxed agent RMW +
// relaxed agent spin (R3-proven live), placement-independent.
template <bool SEQ>
__global__ __launch_bounds__(256, 1)
void gru_main(const ushort_t* __restrict__ xbf,
              const ushort_t* __restrict__ W1t, const ushort_t* __restrict__ R1t,
              const ushort_t* __restrict__ W2t, const ushort_t* __restrict__ R2t,
              const ushort_t* __restrict__ W3t, const ushort_t* __restrict__ R3t,
              const float* __restrict__ b1, const float* __restrict__ b2,
              const float* __restrict__ b3,
              ushort_t* __restrict__ h1s, ushort_t* __restrict__ h2s,
              ushort_t* __restrict__ h3s,
              uint_t* __restrict__ cnt, float* __restrict__ out) {
  __shared__ float scr[2048];   // 7 exchange regions (1792 f) + 2 stages (256 f)
  const int tid = threadIdx.x, bid = blockIdx.x;
  const int grp = bid & 7;
  const int w = bid >> 3;               // 0..31: u-col group
  const int b0A = grp << 5, b0B = b0A + 16;
  const int lane = tid & 63, wid = tid >> 6;
  const int l15 = lane & 15, quad = lane >> 4, q8 = quad << 3;
  const int lay = wid >> 1, sub = wid & 1;
  const bool isC = (w >= 28);
  const int u = (w << 4) + l15;
  const int u3 = ((w - 28) << 4) + l15;
  ushort_t* stg0 = (ushort_t*)&scr[1792];
  ushort_t* stg1 = (ushort_t*)&scr[1920];

  // ---- register-resident weights (union; per-wave interpretation) ----
  short8 wreg[48];
  if (lay == 0) {
    if (sub == 0) {
#pragma unroll
      for (int g = 0; g < 3; ++g) {
#pragma unroll
        for (int kk = 0; kk < 4; ++kk)
          wreg[g * 4 + kk] = *(const short8*)&W1t[(size_t)(g * 512 + u) * 128 + kk * 32 + q8];
#pragma unroll
        for (int kk = 0; kk < 5; ++kk)
          wreg[12 + g * 5 + kk] = *(const short8*)&R1t[(size_t)(g * 512 + u) * 512 + kk * 32 + q8];
      }
    } else {
#pragma unroll
      for (int g = 0; g < 3; ++g)
#pragma unroll
        for (int kk = 0; kk < 11; ++kk)
          wreg[g * 11 + kk] = *(const short8*)&R1t[(size_t)(g * 512 + u) * 512 + (5 + kk) * 32 + q8];
    }
  } else {
#pragma unroll
    for (int g = 0; g < 3; ++g)
#pragma unroll
      for (int kk = 0; kk < 8; ++kk) {
        wreg[g * 8 + kk]      = *(const short8*)&W2t[(size_t)(g * 512 + u) * 512 + (sub * 8 + kk) * 32 + q8];
        wreg[24 + g * 8 + kk] = *(const short8*)&R2t[(size_t)(g * 512 + u) * 512 + (sub * 8 + kk) * 32 + q8];
      }
  }

  // ---- biases ----
  const float bzs1 = b1[u] + b1[1536 + u];
  const float brs1 = b1[512 + u] + b1[2048 + u];
  const float bh10 = b1[1024 + u], bh11 = b1[2560 + u];
  const float bzs2 = b2[u] + b2[1536 + u];
  const float brs2 = b2[512 + u] + b2[2048 + u];
  const float bh20 = b2[1024 + u], bh21 = b2[2560 + u];
  float czs = 0, crs = 0, ch0 = 0, ch1 = 0;
  if (isC) {
    czs = b3[u3] + b3[192 + u3];
    crs = b3[64 + u3] + b3[256 + u3];
    ch0 = b3[128 + u3]; ch1 = b3[320 + u3];
  }

  float h1A[4] = {0,0,0,0}, h2A[4] = {0,0,0,0}, h3A[4] = {0,0,0,0};
  float h1B[4] = {0,0,0,0}, h2B[4] = {0,0,0,0}, h3B[4] = {0,0,0,0};
  const f32x4 z4 = {0.f, 0.f, 0.f, 0.f};
  uint_t* barA = &cnt[(grp * 2) * 16];
  uint_t* barB = &cnt[(grp * 2 + 1) * 16];

  auto run_chain = [&](const int b0, float* hO1, float* hO2, float* hO3, const int s) {
    // slot(t) = t+1 (slot 0 = zeros); ush offsets
    const size_t sl_h1rd = (size_t)(SEQ ? s : (s & 3)) * 131072;          // h1[s-1]
    const size_t sl_h1wr = (size_t)(SEQ ? (s + 1) : ((s + 1) & 3)) * 131072;
    const size_t sl_h2rd = (size_t)(SEQ ? (s - 1) : ((s - 1) & 3)) * 131072; // h2[s-2]
    const size_t sl_h2wr = (size_t)(SEQ ? s : (s & 3)) * 131072;          // h2[s-1]
    const size_t sl_h3rd = (size_t)(SEQ ? (s - 2) : ((s - 2) & 3)) * 16384;  // h3[s-3]
    const size_t sl_h3wr = (size_t)(SEQ ? (s - 1) : ((s - 1) & 3)) * 16384;  // h3[s-2]
    f32x4 az = z4, arr = z4, ahx = z4, ahr = z4;
    f32x4 dz = z4, drr = z4, dhx = z4, dhr = z4;

    if (lay == 0) {
      if (s < 256) {                         // -------- layer1, t = s
        const ushort_t* h1rd = h1s + sl_h1rd;
        if (sub == 0) {
          const ushort_t* xr = xbf + ((size_t)s * 256 + b0 + l15) * 128;
#pragma unroll
          for (int kk = 0; kk < 4; ++kk) {   // x @ W1 (K=128)
            const short8 a = *(const short8*)&xr[kk * 32 + q8];
            az  = MFMA16(a, wreg[kk], az);
            arr = MFMA16(a, wreg[4 + kk], arr);
            ahx = MFMA16(a, wreg[8 + kk], ahx);
          }
#pragma unroll
          for (int kk = 0; kk < 5; ++kk) {   // h1 @ R1, k[0,160)
            const int ko = kk * 32 + q8;
            const short8 a = ldh<SEQ>(&h1rd[(size_t)((ko >> 4) * 256 + b0 + l15) * 16 + (ko & 15)]);
            az  = MFMA16(a, wreg[12 + kk], az);
            arr = MFMA16(a, wreg[17 + kk], arr);
            ahr = MFMA16(a, wreg[22 + kk], ahr);
          }
        } else {
#pragma unroll
          for (int kk = 0; kk < 11; ++kk) {  // h1 @ R1, k[160,512)
            const int ko = (5 + kk) * 32 + q8;
            const short8 a = ldh<SEQ>(&h1rd[(size_t)((ko >> 4) * 256 + b0 + l15) * 16 + (ko & 15)]);
            az  = MFMA16(a, wreg[kk], az);
            arr = MFMA16(a, wreg[11 + kk], arr);
            ahr = MFMA16(a, wreg[22 + kk], ahr);
          }
        }
      }
      if (isC && s >= 2) {                   // -------- layer3, t = s-2
        const ushort_t* h2rd = h2s + sl_h2rd;
        if (sub == 0) {
          const ushort_t* h3rd = h3s + sl_h3rd;
#pragma unroll
          for (int kk = 0; kk < 2; ++kk) {   // h3 @ R3 (K=64)
            const int ko = kk * 32 + q8;
            const short8 a = ldh<SEQ>(&h3rd[(size_t)((ko >> 4) * 256 + b0 + l15) * 16 + (ko & 15)]);
            dz  = MFMA16(a, *(const short8*)&R3t[(size_t)u3 * 64 + ko], dz);
            drr = MFMA16(a, *(const short8*)&R3t[(size_t)(64 + u3) * 64 + ko], drr);
            dhr = MFMA16(a, *(const short8*)&R3t[(size_t)(128 + u3) * 64 + ko], dhr);
          }
#pragma unroll
          for (int kk = 0; kk < 7; ++kk) {   // h2 @ W3, k[0,224)
            const int ko = kk * 32 + q8;
            const short8 a = ldh<SEQ>(&h2rd[(size_t)((ko >> 4) * 256 + b0 + l15) * 16 + (ko & 15)]);
            dz  = MFMA16(a, *(const short8*)&W3t[(size_t)u3 * 512 + ko], dz);
            drr = MFMA16(a, *(const short8*)&W3t[(size_t)(64 + u3) * 512 + ko], drr);
            dhx = MFMA16(a, *(const short8*)&W3t[(size_t)(128 + u3) * 512 + ko], dhx);
          }
        } else {
#pragma unroll
          for (int kk = 7; kk < 16; ++kk) {  // h2 @ W3, k[224,512)
            const int ko = kk * 32 + q8;
            const short8 a = ldh<SEQ>(&h2rd[(size_t)((ko >> 4) * 256 + b0 + l15) * 16 + (ko & 15)]);
            dz  = MFMA16(a, *(const short8*)&W3t[(size_t)u3 * 512 + ko], dz);
            drr = MFMA16(a, *(const short8*)&W3t[(size_t)(64 + u3) * 512 + ko], drr);
            dhx = MFMA16(a, *(const short8*)&W3t[(size_t)(128 + u3) * 512 + ko], dhx);
          }
        }
      }
    } else {
      if (s >= 1 && s < 257) {               // -------- layer2, t = s-1
        const ushort_t* h1rd = h1s + sl_h1rd;
        const ushort_t* h2rd = h2s + sl_h2rd;
#pragma unroll
        for (int k = 0; k < 8; ++k) {        // K-half [sub*256, sub*256+256)
          const int ko = (sub * 8 + k) * 32 + q8;
          const size_t ao = (size_t)((ko >> 4) * 256 + b0 + l15) * 16 + (ko & 15);
          const short8 a1 = ldh<SEQ>(&h1rd[ao]);
          const short8 a2 = ldh<SEQ>(&h2rd[ao]);
          az  = MFMA16(a1, wreg[k], az);
          arr = MFMA16(a1, wreg[8 + k], arr);
          ahx = MFMA16(a1, wreg[16 + k], ahx);
          az  = MFMA16(a2, wreg[24 + k], az);
          arr = MFMA16(a2, wreg[32 + k], arr);
          ahr = MFMA16(a2, wreg[40 + k], ahr);
        }
      }
    }

    // ---- cross-sub exchange ----
    __syncthreads();
    if (lay == 0 && sub == 1 && s < 256) {
      *(f32x4*)&scr[(0 * 64 + lane) * 4] = az;
      *(f32x4*)&scr[(1 * 64 + lane) * 4] = arr;
      *(f32x4*)&scr[(2 * 64 + lane) * 4] = ahr;
    }
    if (lay == 1 && sub == 1 && s >= 1 && s < 257) {
      *(f32x4*)&scr[(3 * 64 + lane) * 4] = az;
      *(f32x4*)&scr[(4 * 64 + lane) * 4] = arr;
      *(f32x4*)&scr[(5 * 64 + lane) * 4] = ahx;
      *(f32x4*)&scr[(6 * 64 + lane) * 4] = ahr;
    }
    __syncthreads();
    if (lay == 0 && sub == 0 && s < 256) {   // layer1 epilogue (relu)
      const f32x4 ez  = *(const f32x4*)&scr[(0 * 64 + lane) * 4];
      const f32x4 er  = *(const f32x4*)&scr[(1 * 64 + lane) * 4];
      const f32x4 ehr = *(const f32x4*)&scr[(2 * 64 + lane) * 4];
#pragma unroll
      for (int r = 0; r < 4; ++r) {
        const float z = sigm(az[r] + ez[r] + bzs1);
        const float rg = sigm(arr[r] + er[r] + brs1);
        const float hh = fmaxf(ahx[r] + bh10 + rg * (ahr[r] + ehr[r] + bh11), 0.f);
        const float hn = z * hO1[r] + (1.f - z) * hh;
        hO1[r] = hn;
        stg0[(quad * 4 + r) * 16 + l15] = f2bf(hn);
      }
      asm volatile("s_waitcnt lgkmcnt(0)" ::: "memory");
      const ull_t v = *(const ull_t*)&stg0[lane * 4];
      stc8(&h1s[sl_h1wr + (size_t)w * 4096 + (size_t)b0 * 16 + lane * 4], v);
    }
    if (lay == 1 && sub == 0 && s >= 1 && s < 257) {  // layer2 epilogue (relu)
      const f32x4 ez  = *(const f32x4*)&scr[(3 * 64 + lane) * 4];
      const f32x4 er  = *(const f32x4*)&scr[(4 * 64 + lane) * 4];
      const f32x4 ehx = *(const f32x4*)&scr[(5 * 64 + lane) * 4];
      const f32x4 ehr = *(const f32x4*)&scr[(6 * 64 + lane) * 4];
#pragma unroll
      for (int r = 0; r < 4; ++r) {
        const float z = sigm(az[r] + ez[r] + bzs2);
        const float rg = sigm(arr[r] + er[r] + brs2);
        const float hh = fmaxf(ahx[r] + ehx[r] + bh20 + rg * (ahr[r] + ehr[r] + bh21), 0.f);
        const float hn = z * hO2[r] + (1.f - z) * hh;
        hO2[r] = hn;
        stg1[(quad * 4 + r) * 16 + l15] = f2bf(hn);
      }
      asm volatile("s_waitcnt lgkmcnt(0)" ::: "memory");
      const ull_t v = *(const ull_t*)&stg1[lane * 4];
      stc8(&h2s[sl_h2wr + (size_t)w * 4096 + (size_t)b0 * 16 + lane * 4], v);
    }
    if (isC) {
      __syncthreads();
      if (lay == 0 && sub == 1 && s >= 2) {
        *(f32x4*)&scr[(0 * 64 + lane) * 4] = dz;
        *(f32x4*)&scr[(1 * 64 + lane) * 4] = drr;
        *(f32x4*)&scr[(2 * 64 + lane) * 4] = dhx;
      }
      __syncthreads();
      if (lay == 0 && sub == 0 && s >= 2) {  // layer3 epilogue (sigmoid)
        const int t3 = s - 2;
        const f32x4 ez  = *(const f32x4*)&scr[(0 * 64 + lane) * 4];
        const f32x4 er  = *(const f32x4*)&scr[(1 * 64 + lane) * 4];
        const f32x4 ehx = *(const f32x4*)&scr[(2 * 64 + lane) * 4];
#pragma unroll
        for (int r = 0; r < 4; ++r) {
          const float z = sigm(dz[r] + ez[r] + czs);
          const float rg = sigm(drr[r] + er[r] + crs);
          const float hh = sigm(dhx[r] + ehx[r] + ch0 + rg * (dhr[r] + ch1));
          const float hn = z * hO3[r] + (1.f - z) * hh;
          hO3[r] = hn;
          out[((size_t)(b0 + quad * 4 + r) * 256 + t3) * 64 + u3] = hn;
          stg0[(quad * 4 + r) * 16 + l15] = f2bf(hn);
        }
        asm volatile("s_waitcnt lgkmcnt(0)" ::: "memory");
        const ull_t v = *(const ull_t*)&stg0[lane * 4];
        stc8(&h3s[sl_h3wr + (size_t)(w - 28) * 4096 + (size_t)b0 * 16 + lane * 4], v);
      }
    }
  };

#pragma unroll 1
  for (int s = 0; s < 258; ++s) {
    // wait A ready (slack: our whole B phase of s-1 -> usually instant)
    if (tid == 0) {
      const uint_t tgt = (uint_t)s * 32u;
      while (__hip_atomic_load(barA, __ATOMIC_RELAXED, __HIP_MEMORY_SCOPE_AGENT) < tgt)
        __builtin_amdgcn_s_sleep(2);
    }
    __syncthreads();
    run_chain(b0A, h1A, h2A, h3A, s);
    __syncthreads();                 // all waves' A stores issued+drained before arrive
    if (tid == 0) {
      __hip_atomic_fetch_add(barA, 1u, __ATOMIC_RELAXED, __HIP_MEMORY_SCOPE_AGENT);
      const uint_t tgt = (uint_t)s * 32u;   // wait B ready (slack: our A phase)
      while (__hip_atomic_load(barB, __ATOMIC_RELAXED, __HIP_MEMORY_SCOPE_AGENT) < tgt)
        __builtin_amdgcn_s_sleep(2);
    }
    __syncthreads();
    run_chain(b0B, h1B, h2B, h3B, s);
    __syncthreads();
    if (tid == 0)
      __hip_atomic_fetch_add(barB, 1u, __ATOMIC_RELAXED, __HIP_MEMORY_SCOPE_AGENT);
  }
}

extern "C" void kernel_launch(void* const* d_in, const int* in_sizes, int n_in,
                              void* d_out, int out_size, void* d_ws, size_t ws_size,
                              hipStream_t stream) {
  const float* x  = (const float*)d_in[0];
  const float* W1 = (const float*)d_in[1];
  const float* R1 = (const float*)d_in[2];
  const float* b1 = (const float*)d_in[3];
  const float* W2 = (const float*)d_in[4];
  const float* R2 = (const float*)d_in[5];
  const float* b2 = (const float*)d_in[6];
  const float* W3 = (const float*)d_in[7];
  const float* R3 = (const float*)d_in[8];
  const float* b3 = (const float*)d_in[9];
  char* ws = (char*)d_ws;
  ushort_t* xbf = (ushort_t*)(ws + OFF_XBF);
  ushort_t* W1t = (ushort_t*)(ws + OFF_W1T);
  ushort_t* R1t = (ushort_t*)(ws + OFF_R1T);
  ushort_t* W2t = (ushort_t*)(ws + OFF_W2T);
  ushort_t* R2t = (ushort_t*)(ws + OFF_R2T);
  ushort_t* W3t = (ushort_t*)(ws + OFF_W3T);
  ushort_t* R3t = (ushort_t*)(ws + OFF_R3T);
  uint_t* cntp  = (uint_t*)(ws + OFF_CNT);

  const bool seq = (ws_size >= SEQ_NEED);
  ushort_t *h1p, *h2p, *h3p;
  if (seq) {
    h1p = (ushort_t*)(ws + OFF_H);
    h2p = (ushort_t*)(ws + OFF_H + H1_BYTES_SEQ);
    h3p = (ushort_t*)(ws + OFF_H + 2UL * H1_BYTES_SEQ);
  } else {
    h1p = (ushort_t*)(ws + OFF_H);
    h2p = (ushort_t*)(ws + OFF_H + H1_BYTES_RING);
    h3p = (ushort_t*)(ws + OFF_H + 2UL * H1_BYTES_RING);
  }

  k_cvtx<<<8192, 256, 0, stream>>>(x, xbf);
  k_tr<<<768, 256, 0, stream>>>(W1, W1t, 128, 1536, 196608);
  k_tr<<<3072, 256, 0, stream>>>(R1, R1t, 512, 1536, 786432);
  k_tr<<<3072, 256, 0, stream>>>(W2, W2t, 512, 1536, 786432);
  k_tr<<<3072, 256, 0, stream>>>(R2, R2t, 512, 1536, 786432);
  k_tr<<<384, 256, 0, stream>>>(W3, W3t, 512, 192, 98304);
  k_tr<<<48, 256, 0, stream>>>(R3, R3t, 64, 192, 12288);
  k_zero<<<546, 256, 0, stream>>>((uint_t*)h1p, (uint_t*)h2p, (uint_t*)h3p, cntp);
  if (seq) {
    gru_main<true><<<256, 256, 0, stream>>>(xbf, W1t, R1t, W2t, R2t, W3t, R3t,
                                            b1, b2, b3, h1p, h2p, h3p, cntp,
                                            (float*)d_out);
  } else {
    gru_main<false><<<256, 256, 0, stream>>>(xbf, W1t, R1t, W2t, R2t, W3t, R3t,
                                             b1, b2, b3, h1p, h2p, h3p, cntp,
                                             (float*)d_out);
  }
}